// Round 13
// baseline (13264.549 us; speedup 1.0000x reference)
//
#include <hip/hip_runtime.h>

#define N_SUP 8192
#define N_QPT 2048
#define UNIT_LDS 41792
#define SMEM_BYTES 138240
#define N_CHUNKS 12288
#define NPROD 4

typedef float v2f __attribute__((ext_vector_type(2)));
typedef unsigned long long u64;

// ---------------------------------------------------------------------------
// Exactness helpers (fma contraction off: index selection must match numpy).
// ---------------------------------------------------------------------------
__device__ __forceinline__ float sumsq3(float x, float y, float z) {
#pragma clang fp contract(off)
  return x * x + y * y + z * z;
}

__device__ __forceinline__ float dot3(float ax, float ay, float az,
                                      float bx, float by, float bz) {
#pragma clang fp contract(off)
  return ax * bx + ay * by + az * bz;
}

__device__ __forceinline__ float d2_expand(float A, float Bn, float d) {
#pragma clang fp contract(off)
  return (A + Bn) - 2.0f * d;
}

template <int CTRL>
__device__ __forceinline__ u64 dppmax64(u64 k) {
  unsigned lo = (unsigned)k, hi = (unsigned)(k >> 32);
  unsigned olo =
      (unsigned)__builtin_amdgcn_update_dpp((int)lo, (int)lo, CTRL, 0xf, 0xf, false);
  unsigned ohi =
      (unsigned)__builtin_amdgcn_update_dpp((int)hi, (int)hi, CTRL, 0xf, 0xf, false);
  u64 o = (((u64)ohi) << 32) | olo;
  return (o > k) ? o : k;
}

__device__ __forceinline__ u64 wavemax_u64(u64 k) {
  k = dppmax64<0x111>(k);
  k = dppmax64<0x112>(k);
  k = dppmax64<0x114>(k);
  k = dppmax64<0x118>(k);
  k = dppmax64<0x142>(k);
  k = dppmax64<0x143>(k);  // lane 63 = wave max
  return k;
}

__device__ __forceinline__ u64 readlane63_u64(u64 v) {
  unsigned lo = (unsigned)__builtin_amdgcn_readlane((int)(unsigned)v, 63);
  unsigned hi = (unsigned)__builtin_amdgcn_readlane((int)(unsigned)(v >> 32), 63);
  return (((u64)hi) << 32) | lo;
}

// ---------------------------------------------------------------------------
// prep: xyz -> SoA + norms; block 0 also zeroes the progress/work counters.
// ---------------------------------------------------------------------------
__global__ __launch_bounds__(256) void prep_xyz_kernel(
    const float* __restrict__ xyz, float* __restrict__ xs,
    float* __restrict__ ys, float* __restrict__ zs, float* __restrict__ bsq,
    int* __restrict__ flags) {
  int p = blockIdx.x * 256 + threadIdx.x;
  float x = xyz[p * 3 + 0];
  float y = xyz[p * 3 + 1];
  float z = xyz[p * 3 + 2];
  xs[p] = x; ys[p] = y; zs[p] = z;
  bsq[p] = sumsq3(x, y, z);
  if (blockIdx.x == 0) {
    flags[threadIdx.x] = 0;
    if (threadIdx.x < 64) flags[256 + threadIdx.x] = 0;
  }
}

// ---------------------------------------------------------------------------
// transpose features (B,64,N) -> (B,N,64)
// ---------------------------------------------------------------------------
__global__ __launch_bounds__(256) void transpose_feats_kernel(
    const float* __restrict__ feats, float* __restrict__ fT) {
  __shared__ float tile[64][65];
  int b = blockIdx.x >> 7;
  int nb = (blockIdx.x & 127) << 6;
  int t = threadIdx.x;
#pragma unroll
  for (int i = 0; i < 16; ++i) {
    int e = i * 256 + t;
    int c = e >> 6, n = e & 63;
    tile[n][c] = feats[(b * 64 + c) * N_SUP + nb + n];
  }
  __syncthreads();
#pragma unroll
  for (int i = 0; i < 16; ++i) {
    int e = i * 256 + t;
    int n = e >> 6, c = e & 63;
    fT[(b * N_SUP + nb + n) * 64 + c] = tile[n][c];
  }
}

// ---------------------------------------------------------------------------
// Ball query, 4 points/lane via float4 (256-pt tiles).
// ---------------------------------------------------------------------------
__device__ __forceinline__ void bq_wave4(int lane, const float* __restrict__ sx,
                                         const float* __restrict__ sy,
                                         const float* __restrict__ sz,
                                         const float* __restrict__ sq,
                                         float qx, float qy, float qz,
                                         float r2, int K,
                                         int* __restrict__ out) {
  const float A = sumsq3(qx, qy, qz);
  int cnt = 0, first = 0;
  const u64 lt = (1ull << lane) - 1ull;
  for (int base = 0; base < N_SUP; base += 256) {
    float4 x4 = ((const float4*)(sx + base))[lane];
    float4 y4 = ((const float4*)(sy + base))[lane];
    float4 z4 = ((const float4*)(sz + base))[lane];
    float4 q4 = ((const float4*)(sq + base))[lane];
    float da = d2_expand(A, q4.x, dot3(qx, qy, qz, x4.x, y4.x, z4.x));
    float db = d2_expand(A, q4.y, dot3(qx, qy, qz, x4.y, y4.y, z4.y));
    float dc = d2_expand(A, q4.z, dot3(qx, qy, qz, x4.z, y4.z, z4.z));
    float dd = d2_expand(A, q4.w, dot3(qx, qy, qz, x4.w, y4.w, z4.w));
    bool i0 = da <= r2, i1 = db <= r2, i2 = dc <= r2, i3 = dd <= r2;
    u64 M0 = __ballot(i0), M1 = __ballot(i1);
    u64 M2 = __ballot(i2), M3 = __ballot(i3);
    int below = __popcll(M0 & lt) + __popcll(M1 & lt) + __popcll(M2 & lt) +
                __popcll(M3 & lt);
    int p0 = cnt + below;
    int p1 = p0 + (i0 ? 1 : 0);
    int p2 = p1 + (i1 ? 1 : 0);
    int p3 = p2 + (i2 ? 1 : 0);
    int nb = base + 4 * lane;
    if (i0 && p0 < K) out[p0] = nb;
    if (i1 && p1 < K) out[p1] = nb + 1;
    if (i2 && p2 < K) out[p2] = nb + 2;
    if (i3 && p3 < K) out[p3] = nb + 3;
    if (cnt == 0) {
      unsigned mn = 0xFFFFFFFFu;
      if (M0) mn = min(mn, (unsigned)(4 * (__ffsll((long long)M0) - 1)));
      if (M1) mn = min(mn, (unsigned)(4 * (__ffsll((long long)M1) - 1) + 1));
      if (M2) mn = min(mn, (unsigned)(4 * (__ffsll((long long)M2) - 1) + 2));
      if (M3) mn = min(mn, (unsigned)(4 * (__ffsll((long long)M3) - 1) + 3));
      if (mn != 0xFFFFFFFFu) first = base + (int)mn;
    }
    cnt += __popcll(M0) + __popcll(M1) + __popcll(M2) + __popcll(M3);
    if (cnt >= K) break;
  }
  for (int p = cnt + lane; p < K; p += 64) out[p] = first;
}

// ---------------------------------------------------------------------------
// Dense layer: lane == row, wave == 16-wide output chunk; weights wave-uniform.
// ---------------------------------------------------------------------------
template <int CIN, int SIN, int D, int SOUT>
__device__ __forceinline__ void dense_layer(const float* __restrict__ hin,
                                            float* __restrict__ hout,
                                            const float* __restrict__ W,
                                            const float* __restrict__ Bv,
                                            int w, int lane) {
  constexpr int CH = D / 16;
#pragma unroll
  for (int pass = 0; pass * 4 < CH; ++pass) {
    const int chunk = pass * 4 + w;
    if (chunk < CH) {
      const int co = chunk * 16;
      float acc[16];
#pragma unroll
      for (int j = 0; j < 16; ++j) acc[j] = Bv[co + j];
      const float* hr = hin + lane * SIN;
      const float* wp = W + co;
#pragma unroll 4
      for (int c = 0; c < CIN; ++c) {
        float a = hr[c];
#pragma unroll
        for (int j = 0; j < 16; ++j) acc[j] = fmaf(a, wp[c * D + j], acc[j]);
      }
      float* ho = hout + lane * SOUT + co;
#pragma unroll
      for (int j = 0; j < 16; ++j) ho[j] = fmaxf(acc[j], 0.0f);
    }
  }
}

// ---------------------------------------------------------------------------
// Consumer body for one 256-thread UNIT (tl = 0..255, um = unit LDS base).
// Exactly 5 block-wide __syncthreads (must match the idle path).
// ---------------------------------------------------------------------------
template <int K, int Q, int C2, int S2, int CHOFF>
__device__ __forceinline__ void consumer_body(
    int tl, int qg0, float r2, char* um, const float* __restrict__ xs,
    const float* __restrict__ ys, const float* __restrict__ zs,
    const float* __restrict__ bsq, const float* __restrict__ fT, float* qxyz,
    int* prog, const float* __restrict__ W1, const float* __restrict__ B1,
    const float* __restrict__ W2, const float* __restrict__ B2,
    const float* __restrict__ W3, const float* __restrict__ B3,
    float* __restrict__ outf) {
  constexpr int S0 = 67, S1 = 65;
  float* smem = (float*)um;
  int* lidx = (int*)(um + 41472);
  float* qc = (float*)(um + 41728);
  float* h1 = smem;
  float* h0 = smem + 64 * S1;
  float* h2 = h0;  // overlays h0 (dead after layer1)
  const int w = __builtin_amdgcn_readfirstlane(tl >> 6);
  const int lane = tl & 63;
  const int b = qg0 >> 11;
  const int need = (qg0 & 2047) + Q;
  int* pp = prog + b * 32;
  while (__hip_atomic_load(pp, __ATOMIC_RELAXED, __HIP_MEMORY_SCOPE_AGENT) <
         need)
    __builtin_amdgcn_s_sleep(32);
  if (tl < Q * 3)
    qc[tl] = __hip_atomic_load(&qxyz[qg0 * 3 + tl], __ATOMIC_RELAXED,
                               __HIP_MEMORY_SCOPE_AGENT);
  __syncthreads();  // 1
  if (w < Q)
    bq_wave4(lane, xs + b * N_SUP, ys + b * N_SUP, zs + b * N_SUP,
             bsq + b * N_SUP, qc[w * 3], qc[w * 3 + 1], qc[w * 3 + 2], r2, K,
             lidx + w * K);
  __syncthreads();  // 2
  if (tl < 192) {
    int r = tl / 3, c2 = tl - r * 3;
    int qi = r / K;
    int n = lidx[r];
    const float* sp = (c2 == 0) ? xs : (c2 == 1) ? ys : zs;
    h0[r * S0 + c2] = sp[b * N_SUP + n] - qc[qi * 3 + c2];
  }
#pragma unroll
  for (int i = 0; i < 4; ++i) {
    int idx = tl + 256 * i;
    int r = idx >> 4, fi = idx & 15;
    int n = lidx[r];
    float4 v = ((const float4*)(fT + (size_t)(b * N_SUP + n) * 64))[fi];
    float* d = h0 + r * S0 + 3 + 4 * fi;
    d[0] = v.x; d[1] = v.y; d[2] = v.z; d[3] = v.w;
  }
  __syncthreads();  // 3
  dense_layer<67, S0, 64, S1>(h0, h1, W1, B1, w, lane);
  __syncthreads();  // 4
  dense_layer<64, S1, C2, S2>(h1, h2, W2, B2, w, lane);
  __syncthreads();  // 5
#pragma unroll
  for (int pass = 0; pass < 2; ++pass) {
    const int co = (pass * 4 + w) * 16;
    float acc[16];
#pragma unroll
    for (int j = 0; j < 16; ++j) acc[j] = B3[co + j];
    const float* hr = h2 + lane * S2;
#pragma unroll 4
    for (int c = 0; c < C2; ++c) {
      float a = hr[c];
#pragma unroll
      for (int j = 0; j < 16; ++j)
        acc[j] = fmaf(a, W3[c * 128 + co + j], acc[j]);
    }
#pragma unroll
    for (int j = 0; j < 16; ++j) acc[j] = fmaxf(acc[j], 0.0f);
#pragma unroll
    for (int off = K / 2; off >= 1; off >>= 1) {
#pragma unroll
      for (int j = 0; j < 16; ++j)
        acc[j] = fmaxf(acc[j], __shfl_xor(acc[j], off));
    }
    if ((lane & (K - 1)) == 0) {
      int qg = qg0 + (lane / K);
      int bo = qg >> 11, s = qg & 2047;
      float* dst = outf + ((bo * 256 + CHOFF + co) * 2048 + s);
#pragma unroll
      for (int j = 0; j < 16; ++j) dst[j * 2048] = acc[j];
    }
  }
}

// ---------------------------------------------------------------------------
// Exchange slot layout (per wave, 32B): 4 self-tagged u64 words
//   s0 = dist<<32 | tag<<26 | invorig   (u64-compare == numpy argmax order;
//        tag bits equal across same-iteration keys so ordering is unchanged)
//   s1 = tag<<32 | x_bits ; s2 = tag<<32 | y_bits ; s3 = tag<<32 | z_bits
// Each word is one atomic ds_write_b64 -> no torn-acceptance possible: a
// reader validates ALL four tags before using anything.
// ---------------------------------------------------------------------------
__device__ __forceinline__ void slot_pub(u64* s, u64 key_tagged, u64 tagw,
                                         float x, float y, float z) {
  __hip_atomic_store(&s[0], key_tagged, __ATOMIC_RELAXED,
                     __HIP_MEMORY_SCOPE_WORKGROUP);
  __hip_atomic_store(&s[1], tagw | (u64)__float_as_uint(x), __ATOMIC_RELAXED,
                     __HIP_MEMORY_SCOPE_WORKGROUP);
  __hip_atomic_store(&s[2], tagw | (u64)__float_as_uint(y), __ATOMIC_RELAXED,
                     __HIP_MEMORY_SCOPE_WORKGROUP);
  __hip_atomic_store(&s[3], tagw | (u64)__float_as_uint(z), __ATOMIC_RELAXED,
                     __HIP_MEMORY_SCOPE_WORKGROUP);
}

__device__ __forceinline__ void slot_fold(const u64* sp, u64 tagv26, u64 tagw,
                                          float& x, float& y, float& z) {
  const u64 TAGM = 0x3Full << 26;
  const u64 HI = 0xFFFFFFFF00000000ull;
  for (;;) {
    __asm__ __volatile__("" ::: "memory");
    u64 bad = 0, bk = 0;
    unsigned bx = 0, by = 0, bz = 0;
    const ulonglong2* v = (const ulonglong2*)sp;
#pragma unroll
    for (int w = 0; w < 8; ++w) {
      ulonglong2 a = v[2 * w], b = v[2 * w + 1];
      bad |= ((a.x ^ tagv26) & TAGM) | ((a.y ^ tagw) & HI) |
             ((b.x ^ tagw) & HI) | ((b.y ^ tagw) & HI);
      bool tk = a.x > bk;
      bk = tk ? a.x : bk;
      bx = tk ? (unsigned)a.y : bx;
      by = tk ? (unsigned)b.x : by;
      bz = tk ? (unsigned)b.y : bz;
    }
    if (bad == 0ull) {
      x = __uint_as_float(bx);
      y = __uint_as_float(by);
      z = __uint_as_float(bz);
      return;
    }
  }
}

// ---------------------------------------------------------------------------
// Bin-sort one batch by 8^3 cell into the LDS staging region (512 threads).
// ---------------------------------------------------------------------------
__device__ __forceinline__ void bin_sort512(
    const float* __restrict__ bx, const float* __restrict__ by,
    const float* __restrict__ bz, float* Psx, float* Psy, float* Psz,
    unsigned short* sorig, unsigned* hist, unsigned* offs, unsigned* cursor,
    int t) {
  hist[t] = 0u;
  __syncthreads();
  for (int j = 0; j < 16; ++j) {
    int n = t + j * 512;
    float x = bx[n], y = by[n], z = bz[n];
    int cell = (min(7, (int)(x * 8.0f)) << 6) | (min(7, (int)(y * 8.0f)) << 3) |
               min(7, (int)(z * 8.0f));
    atomicAdd(&hist[cell], 1u);
  }
  __syncthreads();
  offs[t] = hist[t];
  __syncthreads();
  for (int d = 1; d < 512; d <<= 1) {
    unsigned v = (t >= d) ? offs[t - d] : 0u;
    __syncthreads();
    offs[t] += v;
    __syncthreads();
  }
  cursor[t] = offs[t] - hist[t];
  __syncthreads();
  for (int j = 0; j < 16; ++j) {
    int n = t + j * 512;
    float x = bx[n], y = by[n], z = bz[n];
    int cell = (min(7, (int)(x * 8.0f)) << 6) | (min(7, (int)(y * 8.0f)) << 3) |
               min(7, (int)(z * 8.0f));
    unsigned pos = atomicAdd(&cursor[cell], 1u);
    Psx[pos] = x; Psy[pos] = y; Psz[pos] = z;
    sorig[pos] = (unsigned short)n;
  }
  __syncthreads();
}

// ---------------------------------------------------------------------------
// Interleaved 2-batch FPS producer: 512 threads, batches bA=2*blk (points in
// REGISTERS) and bB=2*blk+1 (points stay in the LDS staging region, re-read
// per dirty sweep). Barrier-free main loop; the two chains' exchange
// latencies are mutually hidden by the other chain's compute. Winner coords
// travel THROUGH the exchange (no 96KB mirror). Skew<=1 parity argument as
// round 10 -> slots never overwritten while needed.
// ---------------------------------------------------------------------------
__device__ void fps_producer_il(const float* __restrict__ xs,
                                const float* __restrict__ ys,
                                const float* __restrict__ zs, float* qxyz,
                                int* prog, char* smraw) {
  const int blk = blockIdx.x;
  const int bA = blk * 2, bB = blk * 2 + 1;
  const int t = threadIdx.x;  // 0..511
  float* Psx = (float*)smraw;                                  // 32 KB
  float* Psy = (float*)(smraw + 32768);                        // 32 KB
  float* Psz = (float*)(smraw + 65536);                        // 32 KB
  unsigned short* sgA = (unsigned short*)(smraw + 98304);      // 16 KB
  unsigned short* sgB = (unsigned short*)(smraw + 114688);     // 16 KB
  u64* slots = (u64*)(smraw + 131072);  // [batch][parity][wave][4] = 1 KB
  unsigned* hist = (unsigned*)(smraw + 132096);
  unsigned* offs = (unsigned*)(smraw + 134144);
  unsigned* cursor = (unsigned*)(smraw + 136192);
  if (t < 128) slots[t] = 0ull;  // tag=0 mismatches iteration 1's tag=1

  const float* bxA = xs + bA * N_SUP;
  const float* byA = ys + bA * N_SUP;
  const float* bzA = zs + bA * N_SUP;
  const float* bxB = xs + bB * N_SUP;
  const float* byB = ys + bB * N_SUP;
  const float* bzB = zs + bB * N_SUP;

  // ---- sort A into staging; load A to registers ----
  bin_sort512(bxA, byA, bzA, Psx, Psy, Psz, sgA, hist, offs, cursor, t);
  v2f pxA[8], pyA[8], pzA[8], dmA[8], dmB[8];
  unsigned Aso[8], Bso[8];
  const int base = t * 16;
#pragma unroll
  for (int j = 0; j < 8; ++j) {
    int p0 = base + 2 * j;
    pxA[j] = (v2f){Psx[p0], Psx[p0 + 1]};
    pyA[j] = (v2f){Psy[p0], Psy[p0 + 1]};
    pzA[j] = (v2f){Psz[p0], Psz[p0 + 1]};
    Aso[j] = ((const unsigned*)sgA)[t * 8 + j];
    dmA[j] = (v2f){1e10f, 1e10f};
    dmB[j] = (v2f){1e10f, 1e10f};
  }
  float loxA = pxA[0].x, hixA = pxA[0].x;
  float loyA = pyA[0].x, hiyA = pyA[0].x;
  float lozA = pzA[0].x, hizA = pzA[0].x;
#pragma unroll
  for (int j = 0; j < 8; ++j) {
    loxA = fminf(loxA, fminf(pxA[j].x, pxA[j].y));
    hixA = fmaxf(hixA, fmaxf(pxA[j].x, pxA[j].y));
    loyA = fminf(loyA, fminf(pyA[j].x, pyA[j].y));
    hiyA = fmaxf(hiyA, fmaxf(pyA[j].x, pyA[j].y));
    lozA = fminf(lozA, fminf(pzA[j].x, pzA[j].y));
    hizA = fmaxf(hizA, fmaxf(pzA[j].x, pzA[j].y));
  }
  __syncthreads();  // A fully read out of staging before B overwrites it

  // ---- sort B into staging (stays resident there) ----
  bin_sort512(bxB, byB, bzB, Psx, Psy, Psz, sgB, hist, offs, cursor, t);
  float loxB = 1e9f, hixB = -1e9f, loyB = 1e9f, hiyB = -1e9f;
  float lozB = 1e9f, hizB = -1e9f;
#pragma unroll
  for (int k = 0; k < 16; ++k) {
    float x = Psx[base + k], y = Psy[base + k], z = Psz[base + k];
    loxB = fminf(loxB, x); hixB = fmaxf(hixB, x);
    loyB = fminf(loyB, y); hiyB = fmaxf(hiyB, y);
    lozB = fminf(lozB, z); hizB = fmaxf(hizB, z);
  }
#pragma unroll
  for (int j = 0; j < 8; ++j) Bso[j] = ((const unsigned*)sgB)[t * 8 + j];
  __syncthreads();  // B resident; slots initialized; enter barrier-free loop

  float tvalA = 1e10f, tvalB = 1e10f;
  u64 tkeyA = 0, tkeyB = 0, wkcA = 0, wkcB = 0;
  bool iamA = false, iamB = false;
  float cwxA = 0, cwyA = 0, cwzA = 0, cwxB = 0, cwyB = 0, cwzB = 0;
  float lxA = bxA[0], lyA = byA[0], lzA = bzA[0];
  float lxB = bxB[0], lyB = byB[0], lzB = bzB[0];
  float* qA = qxyz + bA * N_QPT * 3;
  float* qB = qxyz + bB * N_QPT * 3;
  if (t == 0) {
    qA[0] = lxA; qA[1] = lyA; qA[2] = lzA;
    qB[0] = lxB; qB[1] = lyB; qB[2] = lzB;
  }
  const int wv = t >> 6;

  for (int it = 1; it < N_QPT; ++it) {
    const u64 tagv26 = ((u64)(it & 63)) << 26;
    const u64 tagw = ((u64)(it & 63)) << 32;
    const int par = it & 1;
    // ======== chain A compute (points in registers) ========
    {
      float dxl = fmaxf(fmaxf(loxA - lxA, lxA - hixA), 0.0f);
      float dyl = fmaxf(fmaxf(loyA - lyA, lyA - hiyA), 0.0f);
      float dzl = fmaxf(fmaxf(lozA - lzA, lzA - hizA), 0.0f);
      float db2 = dxl * dxl + dyl * dyl + dzl * dzl;
      bool dirty = db2 < tvalA * 1.0001f + 1e-12f;
      if (__ballot(dirty)) {
        if (dirty) {
          float nx = -lxA, ny = -lyA, nz = -lzA;
          v2f nx2 = (v2f){nx, nx}, ny2 = (v2f){ny, ny}, nz2 = (v2f){nz, nz};
          float lm = -1.0f;
#pragma unroll
          for (int j = 0; j < 8; ++j) {
#pragma clang fp contract(off)
            v2f dx = pxA[j] + nx2;
            v2f dy = pyA[j] + ny2;
            v2f dz = pzA[j] + nz2;
            v2f s = dx * dx + dy * dy;
            s = s + dz * dz;
            v2f nd = __builtin_elementwise_min(dmA[j], s);
            dmA[j] = nd;
            lm = fmaxf(lm, fmaxf(nd.x, nd.y));
          }
          tvalA = lm;
          int pay = -1;
#pragma unroll
          for (int j = 0; j < 8; ++j) {
            if (dmA[j].x == tvalA) {
              int inv = 8191 - (int)(Aso[j] & 0xFFFFu);
              if (inv > pay) {
                pay = inv;
                cwxA = pxA[j].x; cwyA = pyA[j].x; cwzA = pzA[j].x;
              }
            }
            if (dmA[j].y == tvalA) {
              int inv = 8191 - (int)(Aso[j] >> 16);
              if (inv > pay) {
                pay = inv;
                cwxA = pxA[j].y; cwyA = pyA[j].y; cwzA = pzA[j].y;
              }
            }
          }
          tkeyA = (((u64)__float_as_uint(tvalA)) << 32) | (unsigned)pay;
        }
        u64 wm = wavemax_u64(tkeyA);
        wkcA = readlane63_u64(wm);
        iamA = (tkeyA == wkcA);
      }
      if (iamA)
        slot_pub(slots + ((0 * 2 + par) * 8 + wv) * 4, wkcA | tagv26, tagw,
                 cwxA, cwyA, cwzA);
    }
    // ======== chain B compute (points re-read from LDS when dirty) ========
    {
      float dxl = fmaxf(fmaxf(loxB - lxB, lxB - hixB), 0.0f);
      float dyl = fmaxf(fmaxf(loyB - lyB, lyB - hiyB), 0.0f);
      float dzl = fmaxf(fmaxf(lozB - lzB, lzB - hizB), 0.0f);
      float db2 = dxl * dxl + dyl * dyl + dzl * dzl;
      bool dirty = db2 < tvalB * 1.0001f + 1e-12f;
      if (__ballot(dirty)) {
        if (dirty) {
          const float4* fx4 = (const float4*)(Psx + base);
          const float4* fy4 = (const float4*)(Psy + base);
          const float4* fz4 = (const float4*)(Psz + base);
          float nx = -lxB, ny = -lyB, nz = -lzB;
          v2f nx2 = (v2f){nx, nx}, ny2 = (v2f){ny, ny}, nz2 = (v2f){nz, nz};
          float lm = -1.0f;
          float4 Xs[4], Ys[4], Zs[4];
#pragma unroll
          for (int k = 0; k < 4; ++k) {
            Xs[k] = fx4[k]; Ys[k] = fy4[k]; Zs[k] = fz4[k];
          }
#pragma unroll
          for (int k = 0; k < 4; ++k) {
#pragma clang fp contract(off)
            v2f xa = (v2f){Xs[k].x, Xs[k].y}, xb = (v2f){Xs[k].z, Xs[k].w};
            v2f ya = (v2f){Ys[k].x, Ys[k].y}, yb = (v2f){Ys[k].z, Ys[k].w};
            v2f za = (v2f){Zs[k].x, Zs[k].y}, zb = (v2f){Zs[k].z, Zs[k].w};
            v2f dxa = xa + nx2, dya = ya + ny2, dza = za + nz2;
            v2f sa = dxa * dxa + dya * dya;
            sa = sa + dza * dza;
            v2f nda = __builtin_elementwise_min(dmB[2 * k], sa);
            dmB[2 * k] = nda;
            v2f dxb = xb + nx2, dyb = yb + ny2, dzb = zb + nz2;
            v2f sb = dxb * dxb + dyb * dyb;
            sb = sb + dzb * dzb;
            v2f ndb = __builtin_elementwise_min(dmB[2 * k + 1], sb);
            dmB[2 * k + 1] = ndb;
            lm = fmaxf(lm, fmaxf(fmaxf(nda.x, nda.y), fmaxf(ndb.x, ndb.y)));
          }
          tvalB = lm;
          int pay = -1;
#pragma unroll
          for (int k = 0; k < 4; ++k) {
            if (dmB[2 * k].x == tvalB) {
              int inv = 8191 - (int)(Bso[2 * k] & 0xFFFFu);
              if (inv > pay) {
                pay = inv; cwxB = Xs[k].x; cwyB = Ys[k].x; cwzB = Zs[k].x;
              }
            }
            if (dmB[2 * k].y == tvalB) {
              int inv = 8191 - (int)(Bso[2 * k] >> 16);
              if (inv > pay) {
                pay = inv; cwxB = Xs[k].y; cwyB = Ys[k].y; cwzB = Zs[k].y;
              }
            }
            if (dmB[2 * k + 1].x == tvalB) {
              int inv = 8191 - (int)(Bso[2 * k + 1] & 0xFFFFu);
              if (inv > pay) {
                pay = inv; cwxB = Xs[k].z; cwyB = Ys[k].z; cwzB = Zs[k].z;
              }
            }
            if (dmB[2 * k + 1].y == tvalB) {
              int inv = 8191 - (int)(Bso[2 * k + 1] >> 16);
              if (inv > pay) {
                pay = inv; cwxB = Xs[k].w; cwyB = Ys[k].w; cwzB = Zs[k].w;
              }
            }
          }
          tkeyB = (((u64)__float_as_uint(tvalB)) << 32) | (unsigned)pay;
        }
        u64 wm = wavemax_u64(tkeyB);
        wkcB = readlane63_u64(wm);
        iamB = (tkeyB == wkcB);
      }
      if (iamB)
        slot_pub(slots + ((1 * 2 + par) * 8 + wv) * 4, wkcB | tagv26, tagw,
                 cwxB, cwyB, cwzB);
    }
    // ======== exchanges (all publishes precede all folds: no deadlock) ====
    slot_fold(slots + ((0 * 2 + par) * 8) * 4, tagv26, tagw, lxA, lyA, lzA);
    slot_fold(slots + ((1 * 2 + par) * 8) * 4, tagv26, tagw, lxB, lyB, lzB);
    if (t == 0) {
      qA[it * 3 + 0] = lxA; qA[it * 3 + 1] = lyA; qA[it * 3 + 2] = lzA;
      qB[it * 3 + 0] = lxB; qB[it * 3 + 1] = lyB; qB[it * 3 + 2] = lzB;
      if ((it & 63) == 63) {
        __hip_atomic_store(prog + bA * 32, it + 1, __ATOMIC_RELEASE,
                           __HIP_MEMORY_SCOPE_AGENT);
        __hip_atomic_store(prog + bB * 32, it + 1, __ATOMIC_RELEASE,
                           __HIP_MEMORY_SCOPE_AGENT);
      }
    }
  }
}

// ---------------------------------------------------------------------------
// Fused persistent kernel. Grid = 256 blocks x 768 threads (135 KB LDS ->
// 1 block/CU -> all resident: deadlock-free). Blocks 0..3: waves 8-11 exit;
// waves 0-7 run the interleaved 2-batch producer, then exit. Blocks 4..255:
// persistent consumers, THREE independent 256-thread units per block.
// ---------------------------------------------------------------------------
__global__ __launch_bounds__(768) void fused_kernel(
    const float* __restrict__ xs, const float* __restrict__ ys,
    const float* __restrict__ zs, const float* __restrict__ bsq,
    const float* __restrict__ fT, float* qxyz, float* outf, int* prog,
    int* qwork, const float* W10, const float* B10, const float* W11,
    const float* B11, const float* W12, const float* B12, const float* W20,
    const float* B20, const float* W21, const float* B21, const float* W22,
    const float* B22) {
  __shared__ __align__(16) char smraw[SMEM_BYTES];
  if (blockIdx.x < NPROD) {
    if (threadIdx.x < 512) fps_producer_il(xs, ys, zs, qxyz, prog, smraw);
    return;  // producers exit; consumer capacity covers the drain
  }
  const int t = threadIdx.x;
  const int unit = t >> 8;
  const int tl = t & 255;
  char* um = smraw + unit * UNIT_LDS;
  int* lch = (int*)(smraw + 3 * UNIT_LDS);
  for (;;) {
    if (t == 0) {
      int c0 = atomicAdd(qwork, 3);
      lch[0] = c0;
      lch[1] = c0 + 1;
      lch[2] = c0 + 2;
    }
    __syncthreads();  // ticket barrier
    int c = lch[unit];
    if (lch[0] >= N_CHUNKS) return;  // uniform: lch[0] is the smallest ticket
    if (c < N_CHUNKS) {
      int g = c / 3, r = c - g * 3;
      if (r == 0) {
        int qg0 = ((g & 7) << 11) + ((g >> 3) << 2);
        consumer_body<16, 4, 64, 65, 0>(tl, qg0, 0.01f, um, xs, ys, zs, bsq,
                                        fT, qxyz, prog, W10, B10, W11, B11,
                                        W12, B12, outf);
      } else {
        int h = 2 * g + r - 1;
        int qg0 = (((h >> 1) & 7) << 11) + ((h >> 4) << 2) + ((h & 1) << 1);
        consumer_body<32, 2, 96, 97, 128>(tl, qg0, 0.04f, um, xs, ys, zs, bsq,
                                          fT, qxyz, prog, W20, B20, W21, B21,
                                          W22, B22, outf);
      }
    } else {
      // idle unit: match consumer_body's 5 barriers
      __syncthreads();
      __syncthreads();
      __syncthreads();
      __syncthreads();
      __syncthreads();
    }
  }
}

// ---------------------------------------------------------------------------
// ws layout (floats): xs[65536] ys[65536] zs[65536] bsq[65536] fT[4194304]
// then int flags: prog[8*32] + qwork at +256  (~17.8 MB)
// ---------------------------------------------------------------------------
extern "C" void kernel_launch(void* const* d_in, const int* in_sizes, int n_in,
                              void* d_out, int out_size, void* d_ws,
                              size_t ws_size, hipStream_t stream) {
  const float* xyz = (const float*)d_in[0];
  const float* feats = (const float*)d_in[1];
  const float* wt[12];
  for (int i = 0; i < 12; ++i) wt[i] = (const float*)d_in[2 + i];

  float* ws = (float*)d_ws;
  float* xs = ws;
  float* ys = ws + 65536;
  float* zs = ws + 131072;
  float* bsq = ws + 196608;
  float* fT = ws + 262144;              // 4194304 floats
  int* flags = (int*)(ws + 4456448);    // prog[256] + qwork
  int* prog = flags;
  int* qwork = flags + 256;

  float* qxyz = (float*)d_out;          // (8,2048,3)
  float* outf = qxyz + 8 * 2048 * 3;    // (8,256,2048)

  prep_xyz_kernel<<<dim3(256), dim3(256), 0, stream>>>(xyz, xs, ys, zs, bsq,
                                                       flags);
  transpose_feats_kernel<<<dim3(1024), dim3(256), 0, stream>>>(feats, fT);
  fused_kernel<<<dim3(256), dim3(768), 0, stream>>>(
      xs, ys, zs, bsq, fT, qxyz, outf, prog, qwork, wt[0], wt[1], wt[2], wt[3],
      wt[4], wt[5], wt[6], wt[7], wt[8], wt[9], wt[10], wt[11]);
}

// Round 14
// 2269.665 us; speedup vs baseline: 5.8443x; 5.8443x over previous
//
#include <hip/hip_runtime.h>

#define N_SUP 8192
#define N_QPT 2048
#define UNIT_LDS 41792
#define SMEM_BYTES 125440
#define N_CHUNKS 12288

typedef float v2f __attribute__((ext_vector_type(2)));

// ---------------------------------------------------------------------------
// Exactness helpers (fma contraction off: index selection must match numpy).
// ---------------------------------------------------------------------------
__device__ __forceinline__ float sumsq3(float x, float y, float z) {
#pragma clang fp contract(off)
  return x * x + y * y + z * z;
}

__device__ __forceinline__ float dot3(float ax, float ay, float az,
                                      float bx, float by, float bz) {
#pragma clang fp contract(off)
  return ax * bx + ay * by + az * bz;
}

__device__ __forceinline__ float d2_expand(float A, float Bn, float d) {
#pragma clang fp contract(off)
  return (A + Bn) - 2.0f * d;
}

template <int CTRL>
__device__ __forceinline__ unsigned long long dppmax64(unsigned long long k) {
  unsigned lo = (unsigned)k, hi = (unsigned)(k >> 32);
  unsigned olo =
      (unsigned)__builtin_amdgcn_update_dpp((int)lo, (int)lo, CTRL, 0xf, 0xf, false);
  unsigned ohi =
      (unsigned)__builtin_amdgcn_update_dpp((int)hi, (int)hi, CTRL, 0xf, 0xf, false);
  unsigned long long o = (((unsigned long long)ohi) << 32) | olo;
  return (o > k) ? o : k;
}

__device__ __forceinline__ unsigned long long wavemax_u64(unsigned long long k) {
  k = dppmax64<0x111>(k);
  k = dppmax64<0x112>(k);
  k = dppmax64<0x114>(k);
  k = dppmax64<0x118>(k);
  k = dppmax64<0x142>(k);
  k = dppmax64<0x143>(k);  // lane 63 = wave max
  return k;
}

// ---------------------------------------------------------------------------
// prep: xyz -> SoA + norms; block 0 also zeroes the progress/work counters.
// ---------------------------------------------------------------------------
__global__ __launch_bounds__(256) void prep_xyz_kernel(
    const float* __restrict__ xyz, float* __restrict__ xs,
    float* __restrict__ ys, float* __restrict__ zs, float* __restrict__ bsq,
    int* __restrict__ flags) {
  int p = blockIdx.x * 256 + threadIdx.x;
  float x = xyz[p * 3 + 0];
  float y = xyz[p * 3 + 1];
  float z = xyz[p * 3 + 2];
  xs[p] = x; ys[p] = y; zs[p] = z;
  bsq[p] = sumsq3(x, y, z);
  if (blockIdx.x == 0) {
    flags[threadIdx.x] = 0;
    if (threadIdx.x < 64) flags[256 + threadIdx.x] = 0;
  }
}

// ---------------------------------------------------------------------------
// transpose features (B,64,N) -> (B,N,64)
// ---------------------------------------------------------------------------
__global__ __launch_bounds__(256) void transpose_feats_kernel(
    const float* __restrict__ feats, float* __restrict__ fT) {
  __shared__ float tile[64][65];
  int b = blockIdx.x >> 7;
  int nb = (blockIdx.x & 127) << 6;
  int t = threadIdx.x;
#pragma unroll
  for (int i = 0; i < 16; ++i) {
    int e = i * 256 + t;
    int c = e >> 6, n = e & 63;
    tile[n][c] = feats[(b * 64 + c) * N_SUP + nb + n];
  }
  __syncthreads();
#pragma unroll
  for (int i = 0; i < 16; ++i) {
    int e = i * 256 + t;
    int n = e >> 6, c = e & 63;
    fT[(b * N_SUP + nb + n) * 64 + c] = tile[n][c];
  }
}

// ---------------------------------------------------------------------------
// Ball query, 4 points/lane via float4 (256-pt tiles): 4x fewer dependent
// iterations. Exact first-K-by-index via 4-ballot prefix arithmetic.
// ---------------------------------------------------------------------------
__device__ __forceinline__ void bq_wave4(int lane, const float* __restrict__ sx,
                                         const float* __restrict__ sy,
                                         const float* __restrict__ sz,
                                         const float* __restrict__ sq,
                                         float qx, float qy, float qz,
                                         float r2, int K,
                                         int* __restrict__ out) {
  const float A = sumsq3(qx, qy, qz);
  int cnt = 0, first = 0;
  const unsigned long long lt = (1ull << lane) - 1ull;
  for (int base = 0; base < N_SUP; base += 256) {
    float4 x4 = ((const float4*)(sx + base))[lane];
    float4 y4 = ((const float4*)(sy + base))[lane];
    float4 z4 = ((const float4*)(sz + base))[lane];
    float4 q4 = ((const float4*)(sq + base))[lane];
    float da = d2_expand(A, q4.x, dot3(qx, qy, qz, x4.x, y4.x, z4.x));
    float db = d2_expand(A, q4.y, dot3(qx, qy, qz, x4.y, y4.y, z4.y));
    float dc = d2_expand(A, q4.z, dot3(qx, qy, qz, x4.z, y4.z, z4.z));
    float dd = d2_expand(A, q4.w, dot3(qx, qy, qz, x4.w, y4.w, z4.w));
    bool i0 = da <= r2, i1 = db <= r2, i2 = dc <= r2, i3 = dd <= r2;
    unsigned long long M0 = __ballot(i0), M1 = __ballot(i1);
    unsigned long long M2 = __ballot(i2), M3 = __ballot(i3);
    int below = __popcll(M0 & lt) + __popcll(M1 & lt) + __popcll(M2 & lt) +
                __popcll(M3 & lt);
    int p0 = cnt + below;
    int p1 = p0 + (i0 ? 1 : 0);
    int p2 = p1 + (i1 ? 1 : 0);
    int p3 = p2 + (i2 ? 1 : 0);
    int nb = base + 4 * lane;
    if (i0 && p0 < K) out[p0] = nb;
    if (i1 && p1 < K) out[p1] = nb + 1;
    if (i2 && p2 < K) out[p2] = nb + 2;
    if (i3 && p3 < K) out[p3] = nb + 3;
    if (cnt == 0) {
      unsigned mn = 0xFFFFFFFFu;
      if (M0) mn = min(mn, (unsigned)(4 * (__ffsll((long long)M0) - 1)));
      if (M1) mn = min(mn, (unsigned)(4 * (__ffsll((long long)M1) - 1) + 1));
      if (M2) mn = min(mn, (unsigned)(4 * (__ffsll((long long)M2) - 1) + 2));
      if (M3) mn = min(mn, (unsigned)(4 * (__ffsll((long long)M3) - 1) + 3));
      if (mn != 0xFFFFFFFFu) first = base + (int)mn;
    }
    cnt += __popcll(M0) + __popcll(M1) + __popcll(M2) + __popcll(M3);
    if (cnt >= K) break;
  }
  for (int p = cnt + lane; p < K; p += 64) out[p] = first;
}

// ---------------------------------------------------------------------------
// Dense layer: lane == row, wave == 16-wide output chunk; weights wave-uniform.
// ---------------------------------------------------------------------------
template <int CIN, int SIN, int D, int SOUT>
__device__ __forceinline__ void dense_layer(const float* __restrict__ hin,
                                            float* __restrict__ hout,
                                            const float* __restrict__ W,
                                            const float* __restrict__ Bv,
                                            int w, int lane) {
  constexpr int CH = D / 16;
#pragma unroll
  for (int pass = 0; pass * 4 < CH; ++pass) {
    const int chunk = pass * 4 + w;
    if (chunk < CH) {
      const int co = chunk * 16;
      float acc[16];
#pragma unroll
      for (int j = 0; j < 16; ++j) acc[j] = Bv[co + j];
      const float* hr = hin + lane * SIN;
      const float* wp = W + co;
#pragma unroll 4
      for (int c = 0; c < CIN; ++c) {
        float a = hr[c];
#pragma unroll
        for (int j = 0; j < 16; ++j) acc[j] = fmaf(a, wp[c * D + j], acc[j]);
      }
      float* ho = hout + lane * SOUT + co;
#pragma unroll
      for (int j = 0; j < 16; ++j) ho[j] = fmaxf(acc[j], 0.0f);
    }
  }
}

// ---------------------------------------------------------------------------
// Consumer body for one 256-thread UNIT (tl = 0..255, um = unit LDS base).
// Exactly 5 block-wide __syncthreads (must match the idle path).
// ---------------------------------------------------------------------------
template <int K, int Q, int C2, int S2, int CHOFF>
__device__ __forceinline__ void consumer_body(
    int tl, int qg0, float r2, char* um, const float* __restrict__ xs,
    const float* __restrict__ ys, const float* __restrict__ zs,
    const float* __restrict__ bsq, const float* __restrict__ fT, float* qxyz,
    int* prog, const float* __restrict__ W1, const float* __restrict__ B1,
    const float* __restrict__ W2, const float* __restrict__ B2,
    const float* __restrict__ W3, const float* __restrict__ B3,
    float* __restrict__ outf) {
  constexpr int S0 = 67, S1 = 65;
  float* smem = (float*)um;
  int* lidx = (int*)(um + 41472);
  float* qc = (float*)(um + 41728);
  float* h1 = smem;
  float* h0 = smem + 64 * S1;
  float* h2 = h0;  // overlays h0 (dead after layer1)
  const int w = __builtin_amdgcn_readfirstlane(tl >> 6);
  const int lane = tl & 63;
  const int b = qg0 >> 11;
  const int need = (qg0 & 2047) + Q;
  int* pp = prog + b * 32;
  while (__hip_atomic_load(pp, __ATOMIC_RELAXED, __HIP_MEMORY_SCOPE_AGENT) <
         need)
    __builtin_amdgcn_s_sleep(32);
  if (tl < Q * 3)
    qc[tl] = __hip_atomic_load(&qxyz[qg0 * 3 + tl], __ATOMIC_RELAXED,
                               __HIP_MEMORY_SCOPE_AGENT);
  __syncthreads();  // 1
  if (w < Q)
    bq_wave4(lane, xs + b * N_SUP, ys + b * N_SUP, zs + b * N_SUP,
             bsq + b * N_SUP, qc[w * 3], qc[w * 3 + 1], qc[w * 3 + 2], r2, K,
             lidx + w * K);
  __syncthreads();  // 2
  // rel coords: one element per thread for tl<192
  if (tl < 192) {
    int r = tl / 3, c2 = tl - r * 3;
    int qi = r / K;
    int n = lidx[r];
    const float* sp = (c2 == 0) ? xs : (c2 == 1) ? ys : zs;
    h0[r * S0 + c2] = sp[b * N_SUP + n] - qc[qi * 3 + c2];
  }
  // feats: float4 gather, 4 per thread
#pragma unroll
  for (int i = 0; i < 4; ++i) {
    int idx = tl + 256 * i;
    int r = idx >> 4, fi = idx & 15;
    int n = lidx[r];
    float4 v = ((const float4*)(fT + (size_t)(b * N_SUP + n) * 64))[fi];
    float* d = h0 + r * S0 + 3 + 4 * fi;
    d[0] = v.x; d[1] = v.y; d[2] = v.z; d[3] = v.w;
  }
  __syncthreads();  // 3
  dense_layer<67, S0, 64, S1>(h0, h1, W1, B1, w, lane);
  __syncthreads();  // 4
  dense_layer<64, S1, C2, S2>(h1, h2, W2, B2, w, lane);
  __syncthreads();  // 5
#pragma unroll
  for (int pass = 0; pass < 2; ++pass) {
    const int co = (pass * 4 + w) * 16;
    float acc[16];
#pragma unroll
    for (int j = 0; j < 16; ++j) acc[j] = B3[co + j];
    const float* hr = h2 + lane * S2;
#pragma unroll 4
    for (int c = 0; c < C2; ++c) {
      float a = hr[c];
#pragma unroll
      for (int j = 0; j < 16; ++j)
        acc[j] = fmaf(a, W3[c * 128 + co + j], acc[j]);
    }
#pragma unroll
    for (int j = 0; j < 16; ++j) acc[j] = fmaxf(acc[j], 0.0f);
#pragma unroll
    for (int off = K / 2; off >= 1; off >>= 1) {
#pragma unroll
      for (int j = 0; j < 16; ++j)
        acc[j] = fmaxf(acc[j], __shfl_xor(acc[j], off));
    }
    if ((lane & (K - 1)) == 0) {
      int qg = qg0 + (lane / K);
      int bo = qg >> 11, s = qg & 2047;
      float* dst = outf + ((bo * 256 + CHOFF + co) * 2048 + s);
#pragma unroll
      for (int j = 0; j < 16; ++j) dst[j * 2048] = acc[j];
    }
  }
}

// ---------------------------------------------------------------------------
// FPS producer (exact pruned sweep, LDS coord mirror, one barrier/iter,
// in-loop q stores, agent-release progress publish every 64 samples).
// Runs in a 768-thread block: threads 0..511 active, 512..767 barrier-only.
// ---------------------------------------------------------------------------
__device__ void fps_producer(const float* __restrict__ xs,
                             const float* __restrict__ ys,
                             const float* __restrict__ zs, float* qxyz,
                             int* prog, char* smraw) {
  const int b = blockIdx.x;
  const int t = threadIdx.x;
  const bool act = t < 512;
  float* sxL = (float*)smraw;                                // 32 KB
  float* syL = (float*)(smraw + 32768);                      // 32 KB
  float* szL = (float*)(smraw + 65536);                      // 32 KB
  unsigned short* sorig = (unsigned short*)(smraw + 98304);  // 16 KB
  unsigned* hist = (unsigned*)(smraw + 114688);
  unsigned* offs = (unsigned*)(smraw + 116736);
  unsigned* cursor = (unsigned*)(smraw + 118784);
  unsigned long long* skey = (unsigned long long*)(smraw + 120832);  // [2][8]
  const float* bx = xs + b * N_SUP;
  const float* by = ys + b * N_SUP;
  const float* bz = zs + b * N_SUP;

  if (act) hist[t] = 0u;
  __syncthreads();
  if (act) {
    for (int j = 0; j < 16; ++j) {
      int n = t + j * 512;
      float x = bx[n], y = by[n], z = bz[n];
      int cx = min(7, (int)(x * 8.0f));
      int cy = min(7, (int)(y * 8.0f));
      int cz = min(7, (int)(z * 8.0f));
      atomicAdd(&hist[(cx << 6) | (cy << 3) | cz], 1u);
    }
  }
  __syncthreads();
  if (act) offs[t] = hist[t];
  __syncthreads();
  for (int d = 1; d < 512; d <<= 1) {
    unsigned v = 0;
    if (act && t >= d) v = offs[t - d];
    __syncthreads();
    if (act) offs[t] += v;
    __syncthreads();
  }
  if (act) cursor[t] = offs[t] - hist[t];
  __syncthreads();
  if (act) {
    for (int j = 0; j < 16; ++j) {
      int n = t + j * 512;
      float x = bx[n], y = by[n], z = bz[n];
      int cx = min(7, (int)(x * 8.0f));
      int cy = min(7, (int)(y * 8.0f));
      int cz = min(7, (int)(z * 8.0f));
      unsigned pos = atomicAdd(&cursor[(cx << 6) | (cy << 3) | cz], 1u);
      sxL[pos] = x; syL[pos] = y; szL[pos] = z;
      sorig[pos] = (unsigned short)n;
    }
  }
  __syncthreads();

  v2f px[8], py[8], pz[8], dm[8];
  unsigned payx[8], payy[8];
  float lox = 0, hix = 0, loy = 0, hiy = 0, loz = 0, hiz = 0;
  if (act) {
    const int base = t * 16;
#pragma unroll
    for (int j = 0; j < 8; ++j) {
      int p0 = base + 2 * j, p1 = p0 + 1;
      px[j] = (v2f){sxL[p0], sxL[p1]};
      py[j] = (v2f){syL[p0], syL[p1]};
      pz[j] = (v2f){szL[p0], szL[p1]};
      payx[j] = ((unsigned)(N_SUP - 1 - sorig[p0]) << 13) | (unsigned)p0;
      payy[j] = ((unsigned)(N_SUP - 1 - sorig[p1]) << 13) | (unsigned)p1;
      dm[j] = (v2f){1e10f, 1e10f};
    }
    lox = hix = px[0].x;
    loy = hiy = py[0].x;
    loz = hiz = pz[0].x;
#pragma unroll
    for (int j = 0; j < 8; ++j) {
      lox = fminf(lox, fminf(px[j].x, px[j].y));
      hix = fmaxf(hix, fmaxf(px[j].x, px[j].y));
      loy = fminf(loy, fminf(py[j].x, py[j].y));
      hiy = fmaxf(hiy, fmaxf(py[j].x, py[j].y));
      loz = fminf(loz, fminf(pz[j].x, pz[j].y));
      hiz = fmaxf(hiz, fmaxf(pz[j].x, pz[j].y));
    }
  }
  float tval = 1e10f;
  unsigned long long tkey = 0ull, wkey = 0ull;
  float lxp = bx[0], lyp = by[0], lzp = bz[0];
  float* q = qxyz + b * N_QPT * 3;
  if (t == 0) { q[0] = lxp; q[1] = lyp; q[2] = lzp; }
  const int wv = t >> 6;
  const bool is63 = ((t & 63) == 63) && act;

  for (int it = 1; it < N_QPT; ++it) {
    bool dirty = false;
    if (act) {
      float dxl = fmaxf(fmaxf(lox - lxp, lxp - hix), 0.0f);
      float dyl = fmaxf(fmaxf(loy - lyp, lyp - hiy), 0.0f);
      float dzl = fmaxf(fmaxf(loz - lzp, lzp - hiz), 0.0f);
      float db2 = dxl * dxl + dyl * dyl + dzl * dzl;
      dirty = db2 < tval * 1.0001f + 1e-12f;
    }
    if (__ballot(dirty)) {
      if (dirty) {
        float nx = -lxp, ny = -lyp, nz = -lzp;
        v2f nx2 = (v2f){nx, nx}, ny2 = (v2f){ny, ny}, nz2 = (v2f){nz, nz};
        float lm = -1.0f;
#pragma unroll
        for (int j = 0; j < 8; ++j) {
#pragma clang fp contract(off)
          v2f dx = px[j] + nx2;
          v2f dy = py[j] + ny2;
          v2f dz = pz[j] + nz2;
          v2f s = dx * dx + dy * dy;
          s = s + dz * dz;
          v2f nd = __builtin_elementwise_min(dm[j], s);
          dm[j] = nd;
          lm = fmaxf(lm, fmaxf(nd.x, nd.y));
        }
        tval = lm;
        unsigned pay = 0u;
#pragma unroll
        for (int j = 0; j < 8; ++j) {
          if (dm[j].x == tval) pay = max(pay, payx[j]);
          if (dm[j].y == tval) pay = max(pay, payy[j]);
        }
        tkey = (((unsigned long long)__float_as_uint(tval)) << 32) | pay;
      }
      wkey = wavemax_u64(tkey);
    }
    if (is63) skey[(it & 1) * 8 + wv] = wkey;
    __syncthreads();
    const ulonglong2* pk = (const ulonglong2*)(skey + (it & 1) * 8);
    ulonglong2 A = pk[0], B = pk[1], C = pk[2], D = pk[3];
    unsigned long long k0 = (A.y > A.x) ? A.y : A.x;
    unsigned long long k1 = (B.y > B.x) ? B.y : B.x;
    unsigned long long k2 = (C.y > C.x) ? C.y : C.x;
    unsigned long long k3 = (D.y > D.x) ? D.y : D.x;
    k0 = (k1 > k0) ? k1 : k0;
    k2 = (k3 > k2) ? k3 : k2;
    k0 = (k2 > k0) ? k2 : k0;
    unsigned pos = (unsigned)k0 & 0x1FFFu;
    lxp = sxL[pos]; lyp = syL[pos]; lzp = szL[pos];
    if (t == 0) {
      q[it * 3 + 0] = lxp;
      q[it * 3 + 1] = lyp;
      q[it * 3 + 2] = lzp;
      if ((it & 63) == 63)
        __hip_atomic_store(prog + b * 32, it + 1, __ATOMIC_RELEASE,
                           __HIP_MEMORY_SCOPE_AGENT);
    }
  }
  __syncthreads();
}

// ---------------------------------------------------------------------------
// Fused persistent kernel. Grid = 256 blocks x 768 threads (~122.5 KB LDS ->
// 1 block/CU -> all resident: deadlock-free). Blocks 0..7 run fps first,
// then ALL blocks run the consumer loop with THREE independent 256-thread
// units per block (separate LDS regions) -> 3 waves/SIMD.
// Each loop iteration executes exactly 6 block barriers on every path.
// ---------------------------------------------------------------------------
__global__ __launch_bounds__(768) void fused_kernel(
    const float* __restrict__ xs, const float* __restrict__ ys,
    const float* __restrict__ zs, const float* __restrict__ bsq,
    const float* __restrict__ fT, float* qxyz, float* outf, int* prog,
    int* qwork, const float* W10, const float* B10, const float* W11,
    const float* B11, const float* W12, const float* B12, const float* W20,
    const float* B20, const float* W21, const float* B21, const float* W22,
    const float* B22) {
  __shared__ __align__(16) char smraw[SMEM_BYTES];
  if (blockIdx.x < 8) {
    fps_producer(xs, ys, zs, qxyz, prog, smraw);
    // fall through: producers join the consumer pool for the drain
  }
  const int t = threadIdx.x;
  const int unit = t >> 8;
  const int tl = t & 255;
  char* um = smraw + unit * UNIT_LDS;
  int* lch = (int*)(smraw + 3 * UNIT_LDS);
  for (;;) {
    if (t == 0) {
      int c0 = atomicAdd(qwork, 3);
      lch[0] = c0;
      lch[1] = c0 + 1;
      lch[2] = c0 + 2;
    }
    __syncthreads();  // ticket barrier
    int c = lch[unit];
    if (lch[0] >= N_CHUNKS) return;  // uniform: lch[0] is the smallest ticket
    if (c < N_CHUNKS) {
      int g = c / 3, r = c - g * 3;
      if (r == 0) {
        int qg0 = ((g & 7) << 11) + ((g >> 3) << 2);
        consumer_body<16, 4, 64, 65, 0>(tl, qg0, 0.01f, um, xs, ys, zs, bsq,
                                        fT, qxyz, prog, W10, B10, W11, B11,
                                        W12, B12, outf);
      } else {
        int h = 2 * g + r - 1;
        int qg0 = (((h >> 1) & 7) << 11) + ((h >> 4) << 2) + ((h & 1) << 1);
        consumer_body<32, 2, 96, 97, 128>(tl, qg0, 0.04f, um, xs, ys, zs, bsq,
                                          fT, qxyz, prog, W20, B20, W21, B21,
                                          W22, B22, outf);
      }
    } else {
      // idle unit: match consumer_body's 5 barriers
      __syncthreads();
      __syncthreads();
      __syncthreads();
      __syncthreads();
      __syncthreads();
    }
  }
}

// ---------------------------------------------------------------------------
// ws layout (floats): xs[65536] ys[65536] zs[65536] bsq[65536] fT[4194304]
// then int flags: prog[8*32] + qwork at +256  (~17.8 MB)
// ---------------------------------------------------------------------------
extern "C" void kernel_launch(void* const* d_in, const int* in_sizes, int n_in,
                              void* d_out, int out_size, void* d_ws,
                              size_t ws_size, hipStream_t stream) {
  const float* xyz = (const float*)d_in[0];
  const float* feats = (const float*)d_in[1];
  const float* wt[12];
  for (int i = 0; i < 12; ++i) wt[i] = (const float*)d_in[2 + i];

  float* ws = (float*)d_ws;
  float* xs = ws;
  float* ys = ws + 65536;
  float* zs = ws + 131072;
  float* bsq = ws + 196608;
  float* fT = ws + 262144;              // 4194304 floats
  int* flags = (int*)(ws + 4456448);    // prog[256] + qwork
  int* prog = flags;
  int* qwork = flags + 256;

  float* qxyz = (float*)d_out;          // (8,2048,3)
  float* outf = qxyz + 8 * 2048 * 3;    // (8,256,2048)

  prep_xyz_kernel<<<dim3(256), dim3(256), 0, stream>>>(xyz, xs, ys, zs, bsq,
                                                       flags);
  transpose_feats_kernel<<<dim3(1024), dim3(256), 0, stream>>>(feats, fT);
  fused_kernel<<<dim3(256), dim3(768), 0, stream>>>(
      xs, ys, zs, bsq, fT, qxyz, outf, prog, qwork, wt[0], wt[1], wt[2], wt[3],
      wt[4], wt[5], wt[6], wt[7], wt[8], wt[9], wt[10], wt[11]);
}